// Round 3
// baseline (128.453 us; speedup 1.0000x reference)
//
#include <hip/hip_runtime.h>

#define LAMBDA_COORD 5.0f
#define LAMBDA_NOOBJ 0.5f

constexpr int Bn = 64;       // batch
constexpr int An = 10647;    // anchors
constexpr int Cn = 9;        // classes
constexpr int Gn = 50;       // gt boxes
constexpr int PRED_ROW = 5 + Cn;        // 14 floats per anchor row
constexpr int S  = 16;                  // anchor splits
constexpr int AC = (An + S - 1) / S;    // 666 anchors per split
constexpr int ACP = ((AC + 63) / 64) * 64;  // 704, padded (branch-free main loop)
constexpr int GTW = 13;                 // GTs per wave (13+13+13+11 = 50)

// ws layout:
//   partials : Bn*Gn*S float2 (score, idx-as-bits)  = 409600 B
//   bcepart  : Bn*S floats                           = 4096 B
//   img_cnt  : Bn ints                               = 256 B   (memset 0)
//   done_cnt : 1 int                                 = 4 B     (memset 0)
//   accum    : 1 float                               = 4 B     (memset 0)

__global__ __launch_bounds__(256) void yolo_fused(
    const float* __restrict__ pred,     // [B, A, 14]
    const float* __restrict__ bboxes,   // [B, G, 4]
    const int*  __restrict__ classes,   // [B, G]
    float2* __restrict__ partials,      // [B, G, S]
    float* __restrict__ bcepart,        // [B, S]
    int*   __restrict__ img_cnt,        // [B]
    int*   __restrict__ done_cnt,       // [1]
    float* __restrict__ accum,          // [1]
    float* __restrict__ out)            // [1]
{
    const int s = blockIdx.x;
    const int b = blockIdx.y;
    const int a0 = s * AC;
    const int n  = min(AC, An - a0);    // 666 (657 for last split)

    __shared__ float4 sbox[ACP];  // x1,y1,x2,y2
    __shared__ float  sap[ACP];   // area_p
    __shared__ float  sred[4];
    __shared__ int    sfin;

    const int tid  = threadIdx.x;
    const int wave = tid >> 6;
    const int lane = tid & 63;

    // ---- stage anchors into LDS (padded), accumulate partial bce0 sum ----
    const float* prow = pred + (size_t)b * An * PRED_ROW;
    float bce = 0.0f;
    for (int i = tid; i < ACP; i += 256) {
        if (i < n) {
            const float* p = prow + (size_t)(a0 + i) * PRED_ROW;
            const float2* p2 = (const float2*)p;      // 56*a is 8B-aligned
            float2 v0 = p2[0], v1 = p2[1];
            float conf = p[4];
            float hw = 0.5f * v1.x, hh = 0.5f * v1.y;
            float x1 = v0.x - hw, x2 = v0.x + hw;
            float y1 = v0.y - hh, y2 = v0.y + hh;
            sbox[i] = make_float4(x1, y1, x2, y2);
            sap[i]  = (x2 - x1) * (y2 - y1);
            bce -= fmaxf(__logf(1.0f - conf), -100.0f);
        } else {
            // degenerate pad: intersection always 0, never selected (strict >)
            sbox[i] = make_float4(1e30f, 1e30f, 1e30f, 1e30f);
            sap[i]  = 0.0f;
        }
    }
    #pragma unroll
    for (int off = 32; off >= 1; off >>= 1) bce += __shfl_xor(bce, off, 64);
    if (lane == 0) sred[wave] = bce;

    // ---- per-wave GT tile into registers ----
    const int g0 = wave * GTW;
    const int ng = min(GTW, Gn - g0);   // 13,13,13,11

    float gx1[GTW], gy1[GTW], gx2[GTW], gy2[GTW], gc1[GTW];
    const float* bb = bboxes + (size_t)b * Gn * 4;
    #pragma unroll
    for (int j = 0; j < GTW; ++j) {
        int g = (j < ng) ? (g0 + j) : g0;    // pad tail with duplicate GT
        float b0 = bb[g * 4 + 0], b1 = bb[g * 4 + 1];
        float b2 = bb[g * 4 + 2], b3 = bb[g * 4 + 3];
        float gcx = 0.5f * (b0 + b2), gcy = 0.5f * (b1 + b3);
        float gw = b2 - b0, gh = b3 - b1;
        gx1[j] = gcx - gw * 0.5f; gx2[j] = gcx + gw * 0.5f;
        gy1[j] = gcy - gh * 0.5f; gy2[j] = gcy + gh * 0.5f;
        gc1[j] = (gx2[j] - gx1[j]) * (gy2[j] - gy1[j]) + 1e-16f;  // area_g + eps
    }

    float bn[GTW], bd[GTW];
    int   bidx[GTW];
    #pragma unroll
    for (int j = 0; j < GTW; ++j) { bn[j] = 0.0f; bd[j] = 1.0f; bidx[j] = 0; }

    __syncthreads();
    if (tid == 0) bcepart[b * S + s] = sred[0] + sred[1] + sred[2] + sred[3];

    // ---- main scan: branch-free, 13 IoUs per anchor read ----
    for (int base = 0; base < ACP; base += 64) {
        int i = base + lane;
        float4 pb = sbox[i];
        float  ap = sap[i];
        int   idx = a0 + i;
        #pragma unroll
        for (int j = 0; j < GTW; ++j) {
            float iw = fminf(pb.z, gx2[j]) - fmaxf(pb.x, gx1[j]);
            float ih = fminf(pb.w, gy2[j]) - fmaxf(pb.y, gy1[j]);
            iw = fmaxf(iw, 0.0f);
            ih = fmaxf(ih, 0.0f);
            float inter = iw * ih;
            float apc   = ap + gc1[j];
            // argmax of inter/(ap+ag-inter) == argmax of inter/(ap+ag):
            // r -> r/(1+r) monotone; compare fractions by cross-multiply.
            bool take = inter * bd[j] > bn[j] * apc;   // strict >: first max wins
            bn[j]   = take ? inter : bn[j];
            bd[j]   = take ? apc   : bd[j];
            bidx[j] = take ? idx   : bidx[j];
        }
    }

    // ---- cross-lane argmax per GT, write partial ----
    #pragma unroll
    for (int j = 0; j < GTW; ++j) {
        if (j < ng) {
            float score = bn[j] * __builtin_amdgcn_rcpf(bd[j]);  // monotone in iou
            int   idx   = bidx[j];
            #pragma unroll
            for (int off = 1; off < 64; off <<= 1) {
                float os = __shfl_xor(score, off, 64);
                int   oi = __shfl_xor(idx, off, 64);
                if (os > score) { score = os; idx = oi; }
            }
            if (lane == 0)
                partials[((size_t)b * Gn + g0 + j) * S + s] =
                    make_float2(score, __int_as_float(idx));
        }
    }

    // ---- last block per image becomes the finisher (threadFenceReduction) ----
    __syncthreads();                       // drain all this block's stores
    if (tid == 0) {
        __threadfence();                   // device-scope release
        int old = atomicAdd(&img_cnt[b], 1);
        sfin = (old == S - 1);
    }
    __syncthreads();
    if (!sfin) return;
    if (wave != 0) return;                 // finisher work on wave 0 only

    __threadfence();                       // device-scope acquire

    const int g = lane;
    float tot0 = 0.0f;
    #pragma unroll
    for (int ss = 0; ss < S; ++ss) tot0 += bcepart[b * S + ss];  // broadcast loads

    float per_gt = 0.0f;
    int   validf = 0;
    if (g < Gn) {
        int cls = classes[b * Gn + g];
        validf = (cls != -1) ? 1 : 0;

        const float2* pp = partials + ((size_t)b * Gn + g) * S;
        float best = -1.0f;
        int   bi = 0;
        #pragma unroll
        for (int ss = 0; ss < S; ++ss) {
            float2 c = pp[ss];
            if (c.x > best) { best = c.x; bi = __float_as_int(c.y); }
        }

        const float* p = pred + ((size_t)b * An + bi) * PRED_ROW;
        float pcx = p[0], pcy = p[1], pw = p[2], ph = p[3], conf = p[4];

        const float* bbg = bboxes + ((size_t)b * Gn + g) * 4;
        float b0 = bbg[0], b1 = bbg[1], b2 = bbg[2], b3 = bbg[3];
        float gcx = 0.5f * (b0 + b2), gcy = 0.5f * (b1 + b3);
        float gw = b2 - b0, gh = b3 - b1;

        float dx = pcx - gcx, dy = pcy - gcy, dw = pw - gw, dh = ph - gh;
        float coord = LAMBDA_COORD * (dx * dx + dy * dy + dw * dw + dh * dh);

        float conf_obj = -fmaxf(__logf(conf), -100.0f);

        float clsl = 0.0f;
        #pragma unroll
        for (int c = 0; c < Cn; ++c) {
            float pc = p[5 + c];
            float lp = fmaxf(__logf(pc), -100.0f);
            float ln = fmaxf(__logf(1.0f - pc), -100.0f);
            clsl -= (c == cls) ? lp : ln;
        }

        float bce0b = -fmaxf(__logf(1.0f - conf), -100.0f);
        float noobj = LAMBDA_NOOBJ * (tot0 - bce0b);

        per_gt = coord + conf_obj + clsl + noobj;
        if (!validf) per_gt = 0.0f;
    }

    float sum = per_gt;
    int   anyv = validf;
    #pragma unroll
    for (int off = 1; off < 64; off <<= 1) {
        sum  += __shfl_xor(sum, off, 64);
        anyv |= __shfl_xor(anyv, off, 64);
    }
    if (lane == 0) {
        float pi = anyv ? sum : (LAMBDA_NOOBJ * tot0);
        atomicAdd(accum, pi * (1.0f / (float)Bn));
        __threadfence();                   // release accum before done_cnt bump
        int old2 = atomicAdd(done_cnt, 1);
        if (old2 == Bn - 1) {
            float a = atomicAdd(accum, 0.0f);   // coherent read of accumulator
            out[0] = a;
        }
    }
}

extern "C" void kernel_launch(void* const* d_in, const int* in_sizes, int n_in,
                              void* d_out, int out_size, void* d_ws, size_t ws_size,
                              hipStream_t stream) {
    const float* pred    = (const float*)d_in[0];
    const float* bboxes  = (const float*)d_in[1];
    const int*   classes = (const int*)d_in[2];
    float* out = (float*)d_out;

    char* ws = (char*)d_ws;
    size_t off = 0;
    float2* partials = (float2*)(ws + off); off += (size_t)Bn * Gn * S * sizeof(float2);
    float*  bcepart  = (float*)(ws + off);  off += (size_t)Bn * S * sizeof(float);
    int*    img_cnt  = (int*)(ws + off);    off += (size_t)Bn * sizeof(int);
    int*    done_cnt = (int*)(ws + off);    off += sizeof(int);
    float*  accum    = (float*)(ws + off);  off += sizeof(float);

    // zero the control block (img_cnt + done_cnt + accum) — graph-capturable
    hipMemsetAsync(img_cnt, 0, (Bn + 2) * sizeof(int), stream);

    yolo_fused<<<dim3(S, Bn), 256, 0, stream>>>(
        pred, bboxes, classes, partials, bcepart, img_cnt, done_cnt, accum, out);
}